// Round 3
// 59.133 us; speedup vs baseline: 1.0095x; 1.0095x over previous
//
#include <hip/hip_runtime.h>

// KNNInteractionGraph — row-per-wave bitonic selection (R12 config + R14 dead
// stage cut; best measured 59.69us total, of which ~40us is the harness's
// 256MiB workspace re-poison fill at HBM roofline — untouchable).
// N=8192, K=32, CUTOFF=10, batch sorted (molecules contiguous, n ~ 64+-8).
//
// Ledger (R5-R14): kernel ~10-20us, latency-bound on the per-wave dependent
// chain; WG count / wave count (both directions) / spills / per-wave dispatch
// all measured neutral; only cross-lane+VALU cuts paid (R8/R11/R12/R14).
// R15: eliminate ALL ds_bpermute from the sort chain (permlane{16,32}_swap for
// j=16/32, DPP pairs for j=4). FAILED: j=4 select was inverted (row_shr:N
// delivers src[lane-N], row_shl:N delivers src[lane+N] — the AMD DPP scan
// convention). R16: fix the j=4 ternary only; rest identical. R17 (this round):
// identical resubmit of R16 — R2's bench was an infra flake ("container failed
// twice"), the kernel never ran.
// Bit-identical outputs vs R14 (keys distinct; min/max-select == compare-select).
//
// Output (float32, 3*N*K): [indices | centers | weights].

#define CUTOFF_F 10.0f
#define ROWS_PER_BLOCK 4
#define KEY_TRUNC 0xFFFFFF80u     // keep 25 high bits of v, low 7 bits = col

typedef unsigned u32x2_t __attribute__((ext_vector_type(2)));

__device__ __forceinline__ float readlane_f(float v, int lane) {
    return __int_as_float(__builtin_amdgcn_readlane(__float_as_int(v), lane));
}
__device__ __forceinline__ int readlane_i(int v, int lane) {
    return __builtin_amdgcn_readlane(v, lane);
}
__device__ __forceinline__ float bperm_f(float v, int srclane) {
    return __int_as_float(__builtin_amdgcn_ds_bpermute(srclane << 2, __float_as_int(v)));
}

// DPP permutations (all lanes active, EXEC=~0):
//   quad_perm xor1 = 0xB1, quad_perm xor2 = 0x4E, row_ror:8 = 0x128 (xor8
//   within 16-lane rows), row_shl:4 = 0x104 (src[lane+4]),
//   row_shr:4 = 0x114 (src[lane-4]).
template <int CTRL>
__device__ __forceinline__ unsigned dpp_u32(unsigned x) {
    return (unsigned)__builtin_amdgcn_update_dpp((int)x, (int)x, CTRL, 0xf, 0xf, true);
}

// permlane{16,32}_swap_b32(key,key): the two results hold {self, partner} in
// every lane (pair order varies by half, but min/max is order-insensitive), so
// per-lane min/max of the pair == min/max(key, key[lane^J]). One cross-lane
// VALU op, no LDS.
__device__ __forceinline__ void swap_minmax16(unsigned key, unsigned& mn, unsigned& mx) {
#if __has_builtin(__builtin_amdgcn_permlane16_swap)
    u32x2_t r = __builtin_amdgcn_permlane16_swap(key, key, false, false);
    mn = min(r.x, r.y); mx = max(r.x, r.y);
#else
    unsigned a = key, b = key;
    asm("v_permlane16_swap_b32 %0, %1" : "+v"(a), "+v"(b));
    mn = min(a, b); mx = max(a, b);
#endif
}
__device__ __forceinline__ void swap_minmax32(unsigned key, unsigned& mn, unsigned& mx) {
#if __has_builtin(__builtin_amdgcn_permlane32_swap)
    u32x2_t r = __builtin_amdgcn_permlane32_swap(key, key, false, false);
    mn = min(r.x, r.y); mx = max(r.x, r.y);
#else
    unsigned a = key, b = key;
    asm("v_permlane32_swap_b32 %0, %1" : "+v"(a), "+v"(b));
    mn = min(a, b); mx = max(a, b);
#endif
}

// One bitonic compare-exchange partner pair as {min,max}. j folds to a
// compile-time constant under full unroll. Pure VALU/DPP for all j in
// {1,2,4,8,16,32} — no ds_bpermute.
__device__ __forceinline__ void stage_minmax(unsigned key, int j, int lane,
                                             unsigned& mn, unsigned& mx) {
    if (j == 32) { swap_minmax32(key, mn, mx); return; }
    if (j == 16) { swap_minmax16(key, mn, mx); return; }
    unsigned p;
    if (j == 1)      p = dpp_u32<0xB1>(key);
    else if (j == 2) p = dpp_u32<0x4E>(key);
    else if (j == 8) p = dpp_u32<0x128>(key);
    else if (j == 4) {
        // xor4: lanes with (lane&4) need src[lane-4] -> row_shr:4 (valid for
        // lane%16>=4); lanes without need src[lane+4] -> row_shl:4 (valid for
        // lane%16<=11). (R15 had this ternary inverted.)
        const unsigned sl = dpp_u32<0x104>(key);   // src[lane+4]
        const unsigned sr = dpp_u32<0x114>(key);   // src[lane-4]
        p = (lane & 4) ? sr : sl;
    } else {
        p = (unsigned)__shfl_xor((int)key, j, 64);   // unreachable; safety net
    }
    mn = min(p, key); mx = max(p, key);
}

// Reference-exact masked distance (gram expansion, f32, no FMA contraction):
__device__ __forceinline__ float dist_v(float4 pr, float4 pc, bool diag) {
    if (diag) return CUTOFF_F;
    float dot = __fadd_rn(__fadd_rn(__fmul_rn(pr.x, pc.x), __fmul_rn(pr.y, pc.y)),
                          __fmul_rn(pr.z, pc.z));
    float sq = __fsub_rn(__fadd_rn(pr.w, pc.w), __fadd_rn(dot, dot));
    sq = fmaxf(sq, 0.0f);
    float d = (sq > 0.0f) ? __fsqrt_rn(sq) : 0.0f;
    return (d > CUTOFF_F) ? CUTOFF_F : d;
}

__device__ __forceinline__ float4 load_pos4(const float* __restrict__ pos, int g) {
    float x = pos[g * 3 + 0];
    float y = pos[g * 3 + 1];
    float z = pos[g * 3 + 2];
    float sq = __fadd_rn(__fadd_rn(__fmul_rn(x, x), __fmul_rn(y, y)), __fmul_rn(z, z));
    return make_float4(x, y, z, sq);
}

// Ascending bitonic sort of 64 u32 keys, one per lane. Keys are distinct
// (low 7 bits = column), so min/max-select == the compare-select it replaces.
__device__ __forceinline__ unsigned bitonic64_u32(unsigned key, int lane) {
#pragma unroll
    for (int k = 2; k <= 64; k <<= 1) {
#pragma unroll
        for (int j = k >> 1; j > 0; j >>= 1) {
            unsigned mn, mx;
            stage_minmax(key, j, lane, mn, mx);
            const bool take_min = (((lane & j) == 0) == ((lane & k) == 0));
            key = take_min ? mn : mx;
        }
    }
    return key;
}

// Ascending bitonic sort of 128 u32 keys, two per lane (A: vpos=lane,
// B: vpos=64+lane). If need_b is false (K<=64), the final-merge tail stages on
// kb are skipped: after the k=128 j=64 in-lane exchange, lower/upper halves are
// independent for j<64, and slots >=64 (kb) are never read.
__device__ __forceinline__ void bitonic128_u32(unsigned& ka, unsigned& kb, int lane,
                                               bool need_b) {
#pragma unroll
    for (int k = 2; k <= 128; k <<= 1) {
#pragma unroll
        for (int j = k >> 1; j > 0; j >>= 1) {
            if (j == 64) {            // final k=128 merge: in-lane A<->B
                const unsigned mn = min(ka, kb);
                const unsigned mx = max(ka, kb);
                ka = mn; kb = mx;
            } else {
                const bool low = ((lane & j) == 0);
                const bool upA = ((lane & k) == 0);
                const bool upB = (k == 64) ? false : upA;
                unsigned mnA, mxA;
                stage_minmax(ka, j, lane, mnA, mxA);
                ka = (low == upA) ? mnA : mxA;
                if (k < 128 || need_b) {          // kb tail dead for K<=64
                    unsigned mnB, mxB;
                    stage_minmax(kb, j, lane, mnB, mxB);
                    kb = (low == upB) ? mnB : mxB;
                }
            }
        }
    }
}

// Cold fill: slots [m,K) get CUTOFF at globally-smallest masked indices:
// {0..start-1} U {in-mol masked (v==CUTOFF)} U {end..N-1} (lax.top_k tie order).
template <int NCH>
__device__ __forceinline__ void do_fill(const float* v, int m, int K, int lane,
                                        int start, int end, int n, int r, int NK,
                                        float* __restrict__ out) {
    const int mm = n - m;
    for (int fb = 0; fb < K - m; fb += 64) {
        const int t = fb + lane;
        const bool active = t < (K - m);
        int idx = 0;
        bool found = false;
        if (active) {
            if (t < start)            { idx = t;                      found = true; }
            else if (t - start >= mm) { idx = end + (t - start - mm); found = true; }
        }
        if (__any(active && !found)) {
            int cnt = 0;
#pragma unroll
            for (int jj = 0; jj < NCH; ++jj) {
                const int base = 64 * jj;
                const int lim  = min(n - base, 64);
                for (int cc = 0; cc < lim; ++cc) {
                    if (readlane_f(v[jj], cc) == CUTOFF_F) {
                        if (active && !found && cnt == t - start) {
                            idx = start + base + cc; found = true;
                        }
                        ++cnt;
                    }
                }
            }
        }
        if (active) {
            const int o = r * K + m + t;
            out[o]          = (float)idx;
            out[2 * NK + o] = CUTOFF_F;
        }
    }
}

// ---------------- hot cores ---------------------------------------------------
__device__ __forceinline__ void row_core_sort64(const float* __restrict__ pos,
                                                int n, int lane,
                                                int start, int end, int r,
                                                float* __restrict__ out,
                                                int NK, int K) {
    const int c = lane;
    const int d = r - start;                       // uniform, in [0, n)
    const int g = start + min(c, n - 1);           // clamped column load
    const float x = pos[g * 3 + 0];
    const float y = pos[g * 3 + 1];
    const float z = pos[g * 3 + 2];
    const float sq = __fadd_rn(__fadd_rn(__fmul_rn(x, x), __fmul_rn(y, y)),
                               __fmul_rn(z, z));
    const float4 pc = make_float4(x, y, z, sq);
    const float4 pr = make_float4(readlane_f(x, d), readlane_f(y, d),
                                  readlane_f(z, d), readlane_f(sq, d));
    float v[1];
    v[0] = (c < n && c != d) ? dist_v(pr, pc, false) : CUTOFF_F;

    unsigned key = (((unsigned)__float_as_int(v[0])) & KEY_TRUNC) | (unsigned)c;
    key = bitonic64_u32(key, lane);

    const int   cs = (int)(key & 0x7Fu);
    const float vx = bperm_f(v[0], cs);            // exact weight by sorted col
    if (lane < K && vx < CUTOFF_F) {               // sorted slot = lane (coalesced)
        const int o = r * K + lane;
        out[o]          = (float)(start + cs);
        out[2 * NK + o] = vx;
    }
    for (int k2 = lane; k2 < K; k2 += 64)          // centers chunk
        out[NK + r * K + k2] = (float)r;
    const int m = __popcll(__ballot(v[0] < CUTOFF_F));
    if (m < K) do_fill<1>(v, m, K, lane, start, end, n, r, NK, out);
}

__device__ __forceinline__ void row_core_sort128(const float* __restrict__ pos,
                                                 int n, int lane,
                                                 int start, int end, int r,
                                                 float* __restrict__ out,
                                                 int NK, int K) {
    const int cA = lane, cB = 64 + lane;
    const int d  = r - start;                      // uniform, in [0, n)
    const int gA = start + min(cA, n - 1);
    const int gB = start + min(cB, n - 1);
    const float xa = pos[gA * 3 + 0], ya = pos[gA * 3 + 1], za = pos[gA * 3 + 2];
    const float xb = pos[gB * 3 + 0], yb = pos[gB * 3 + 1], zb = pos[gB * 3 + 2];
    const float sqa = __fadd_rn(__fadd_rn(__fmul_rn(xa, xa), __fmul_rn(ya, ya)),
                                __fmul_rn(za, za));
    const float sqb = __fadd_rn(__fadd_rn(__fmul_rn(xb, xb), __fmul_rn(yb, yb)),
                                __fmul_rn(zb, zb));
    float4 pr;
    if (d < 64) pr = make_float4(readlane_f(xa, d), readlane_f(ya, d),
                                 readlane_f(za, d), readlane_f(sqa, d));
    else        pr = make_float4(readlane_f(xb, d - 64), readlane_f(yb, d - 64),
                                 readlane_f(zb, d - 64), readlane_f(sqb, d - 64));
    float v[2];
    v[0] = (cA < n && cA != d) ? dist_v(pr, make_float4(xa, ya, za, sqa), false)
                               : CUTOFF_F;
    v[1] = (cB < n && cB != d) ? dist_v(pr, make_float4(xb, yb, zb, sqb), false)
                               : CUTOFF_F;

    unsigned ka = (((unsigned)__float_as_int(v[0])) & KEY_TRUNC) | (unsigned)cA;
    unsigned kb = (((unsigned)__float_as_int(v[1])) & KEY_TRUNC) | (unsigned)cB;
    bitonic128_u32(ka, kb, lane, /*need_b=*/(K > 64));

    const int   csa = (int)(ka & 0x7Fu);
    const float g0  = bperm_f(v[0], csa & 63);
    const float g1  = bperm_f(v[1], csa & 63);
    const float vxa = (csa < 64) ? g0 : g1;        // exact weight
    if (lane < K && vxa < CUTOFF_F) {
        const int o = r * K + lane;
        out[o]          = (float)(start + csa);
        out[2 * NK + o] = vxa;
    }
    if (64 + lane < K) {                           // only reachable when K>64
        const int   csb = (int)(kb & 0x7Fu);
        const float h0  = bperm_f(v[0], csb & 63);
        const float h1  = bperm_f(v[1], csb & 63);
        const float vxb = (csb < 64) ? h0 : h1;
        if (vxb < CUTOFF_F) {
            const int o = r * K + 64 + lane;
            out[o]          = (float)(start + csb);
            out[2 * NK + o] = vxb;
        }
    }
    for (int k2 = lane; k2 < K; k2 += 64)
        out[NK + r * K + k2] = (float)r;
    const int m = __popcll(__ballot(v[0] < CUTOFF_F))
                + __popcll(__ballot(v[1] < CUTOFF_F));
    if (m < K) do_fill<2>(v, m, K, lane, start, end, n, r, NK, out);
}

// ------------- cold paths: own register allocation (noinline) -----------------
__device__ __attribute__((noinline))
int lower_bound_cold(const int* __restrict__ batch, int lo, int hi, int key) {
    while (lo < hi) {
        int mid = (lo + hi) >> 1;
        if (batch[mid] < key) lo = mid + 1; else hi = mid;
    }
    return lo;
}

__device__ __attribute__((noinline))
void row_core_fallback(const float* __restrict__ pos, float4 pr, int n, int lane,
                       int start, int end, int r, float* __restrict__ out,
                       int NK, int K) {
    // exact rank-based path for n > 128 (never taken with bench inputs)
    int m = 0;
    for (int cb = 0; cb < n; cb += 64) {
        const int c = cb + lane;
        const float v = (c < n)
            ? dist_v(pr, load_pos4(pos, start + c), (start + c) == r) : CUTOFF_F;
        int rk = 0;
        for (int cc = 0; cc < n; ++cc) {
            const float vv = dist_v(pr, load_pos4(pos, start + cc), (start + cc) == r);
            rk += (vv < v) || (vv == v && cc < c);
        }
        if (c < n && v < CUTOFF_F && rk < K) {
            const int o = r * K + rk;
            out[o]          = (float)(start + c);
            out[2 * NK + o] = v;
        }
        m += __popcll(__ballot(c < n && v < CUTOFF_F));
    }
    for (int k2 = lane; k2 < K; k2 += 64)
        out[NK + r * K + k2] = (float)r;
    if (m < K) {
        const int mm = n - m;
        for (int fb = 0; fb < K - m; fb += 64) {
            const int t = fb + lane;
            const bool active = t < (K - m);
            int idx = 0; bool found = false;
            if (active) {
                if (t < start)            { idx = t;                      found = true; }
                else if (t - start >= mm) { idx = end + (t - start - mm); found = true; }
            }
            if (__any(active && !found)) {
                int cnt = 0;
                for (int cc = 0; cc < n; ++cc) {
                    if (dist_v(pr, load_pos4(pos, start + cc), (start + cc) == r)
                        == CUTOFF_F) {
                        if (active && !found && cnt == t - start) {
                            idx = start + cc; found = true;
                        }
                        ++cnt;
                    }
                }
            }
            if (active) {
                const int o = r * K + m + t;
                out[o]          = (float)idx;
                out[2 * NK + o] = CUTOFF_F;
            }
        }
    }
}

// ---------------- kernel ------------------------------------------------------
__global__ __launch_bounds__(256, 8)
void knn_fused_kernel(const float* __restrict__ pos,
                      const int* __restrict__ batch,
                      float* __restrict__ out,
                      int N, int K) {
    const int w    = threadIdx.x >> 6;
    const int lane = threadIdx.x & 63;
    const int r    = blockIdx.x * ROWS_PER_BLOCK + w;
    if (r >= N) return;                       // no shared vars, no barriers
    const int NK = N * K;

    const int iu = r - 63 + lane;             // upward window: idx r-63 .. r
    const int id = r + 1 + lane;              // downward window: idx r+1 .. r+64
    const int au = batch[max(iu, 0)];
    const int ad = batch[min(id, N - 1)];

    const int b = readlane_i(au, 63);         // batch[r]

    const unsigned long long mu = __ballot(iu >= 0 && au == b);
    int start;
    if (mu != ~0ull) {
        start = r - __builtin_clzll(~mu) + 1;
    } else {
        const int iu2 = r - 127 + lane;
        const unsigned long long mu2 =
            __ballot(iu2 >= 0 && batch[max(iu2, 0)] == b);
        if (mu2 != ~0ull)           start = r - 63 - __builtin_clzll(~mu2);
        else if (r - 127 <= 0)      start = 0;
        else                        start = lower_bound_cold(batch, 0, r, b);
    }

    const unsigned long long md = __ballot(id < N && ad == b);
    int end;
    if (md != ~0ull) {
        end = r + 1 + __builtin_ctzll(~md);
    } else {
        const int id2 = r + 65 + lane;
        const unsigned long long md2 =
            __ballot(id2 < N && batch[min(id2, N - 1)] == b);
        if (md2 != ~0ull)           end = r + 65 + __builtin_ctzll(~md2);
        else if (r + 129 >= N)      end = N;
        else                        end = lower_bound_cold(batch, r + 1, N, b + 1);
    }

    const int n = end - start;

    if      (n <= 64)  row_core_sort64 (pos, n, lane, start, end, r, out, NK, K);
    else if (n <= 128) row_core_sort128(pos, n, lane, start, end, r, out, NK, K);
    else               row_core_fallback(pos, load_pos4(pos, r), n, lane, start,
                                         end, r, out, NK, K);
}

extern "C" void kernel_launch(void* const* d_in, const int* in_sizes, int n_in,
                              void* d_out, int out_size, void* d_ws, size_t ws_size,
                              hipStream_t stream) {
    const float* pos   = (const float*)d_in[0];   // [N,3] float32
    const int*   batch = (const int*)d_in[1];     // [N]   int32, sorted
    float*       out   = (float*)d_out;           // float32, 3*N*K

    const int N = in_sizes[1];            // 8192
    const int K = out_size / (3 * N);     // 32

    const int grid = (N + ROWS_PER_BLOCK - 1) / ROWS_PER_BLOCK;  // 2048
    knn_fused_kernel<<<grid, 256, 0, stream>>>(pos, batch, out, N, K);
}